// Round 11
// baseline (3615.388 us; speedup 1.0000x reference)
//
#include <hip/hip_runtime.h>
#include <cstddef>

#define T_STEPS  256
#define NSAT     1024
#define GSAT     2048
#define HID      256
#define IN_DIM   32
#define KTOT     288   // 256 h_sat + 32 x_sat

typedef short  s16x8 __attribute__((ext_vector_type(8)));
typedef short  s16x4 __attribute__((ext_vector_type(4)));
typedef float  f32x4 __attribute__((ext_vector_type(4)));
typedef unsigned short ushort_t;

__device__ inline ushort_t f2bf(float f) {
    unsigned u = __builtin_bit_cast(unsigned, f);
    u += 0x7fffu + ((u >> 16) & 1u);
    return (ushort_t)(u >> 16);
}
__device__ inline float bf2f(ushort_t h) {
    unsigned u = ((unsigned)h) << 16;
    return __builtin_bit_cast(float, u);
}
__device__ inline float sigm(float x) { return 1.f / (1.f + __expf(-x)); }
__device__ inline float tanh_(float x) {
    float a = fabsf(x);
    float e = __expf(-2.f * a);
    float r = (1.f - e) / (1.f + e);
    return copysignf(r, x);
}

// ---------------- init: zero prefix ----------------
__global__ void k_zero(float* p, size_t n) {
    size_t i = (size_t)blockIdx.x * blockDim.x + threadIdx.x;
    size_t stride = (size_t)gridDim.x * blockDim.x;
    for (; i < n; i += stride) p[i] = 0.f;
}

// col order: c = (o>>3)*32 + g*8 + (o&7)  <->  g=(c>>3)&3, o=(c>>5)*8+(c&7)
__global__ void k_bconv(const float* __restrict__ r2s_rw,
                        const float* __restrict__ W_sat,
                        ushort_t* __restrict__ BsatT) {
    int c = blockIdx.x;
    int g = (c >> 3) & 3, o = (c >> 5) * 8 + (c & 7);
    for (int k = threadIdx.x; k < KTOT; k += 256) {
        float v = (k < 256) ? r2s_rw[((size_t)g * 256 + k) * 256 + o]
                            : W_sat[((size_t)g * 32 + (k - 256)) * 256 + o];
        BsatT[(size_t)c * KTOT + k] = f2bf(v);
    }
}

// rlwT2[h][c] = r2s_lw[g][h][o] (h-major for rec-side partial products)
__global__ void k_rlw2(const float* __restrict__ r2s_lw, ushort_t* __restrict__ rlwT2) {
    int h = blockIdx.x;
    for (int c = threadIdx.x; c < 1024; c += 256) {
        int g = (c >> 3) & 3, o = (c >> 5) * 8 + (c & 7);
        rlwT2[(size_t)h * 1024 + c] = f2bf(r2s_lw[((size_t)g * 256 + h) * 256 + o]);
    }
}

__global__ void k_biasC(const float* __restrict__ r2s_lb, const float* __restrict__ b_sat,
                        float* __restrict__ biasC) {
    int c = blockIdx.x * 256 + threadIdx.x;
    if (c < 1024) {
        int g = (c >> 3) & 3, o = (c >> 5) * 8 + (c & 7);
        biasC[c] = r2s_lb[g * 256 + o] + b_sat[g * 256 + o];
    }
}

__global__ void k_inv(const int* __restrict__ s_ids, ushort_t* __restrict__ pos_inv) {
    int t = blockIdx.x;
    for (int n = threadIdx.x; n < NSAT; n += 256)
        pos_inv[(size_t)t * GSAT + s_ids[(size_t)t * NSAT + n]] = (ushort_t)(n + 1);
}

// merged index precompute: asrc, nxt_bits, old list, leave list (per t)
__global__ void k_idx(const int* __restrict__ s_ids, const ushort_t* __restrict__ pos_inv,
                      int* __restrict__ asrc, unsigned* __restrict__ nxt_bits,
                      short* __restrict__ old_src, int* __restrict__ old_cnt,
                      int* __restrict__ lv, int* __restrict__ lv_cnt) {
    int t = blockIdx.x, tid = threadIdx.x;
    // asrc[t][n]
    for (int n = tid; n < NSAT; n += 256) {
        int j = s_ids[(size_t)t * NSAT + n];
        int e = 1024 + j;
        if (t > 0) {
            int p = (int)pos_inv[(size_t)(t - 1) * GSAT + j] - 1;
            if (p >= 0) e = p;
        }
        asrc[(size_t)t * NSAT + n] = e;
    }
    // nxt_bits[t][w]
    if (tid < 32) {
        unsigned bits = 0;
        if (t + 1 < T_STEPS) {
            for (int i = 0; i < 32; i++) {
                int j = s_ids[(size_t)t * NSAT + tid * 32 + i];
                if (pos_inv[(size_t)(t + 1) * GSAT + j] > 0) bits |= (1u << i);
            }
        }
        nxt_bits[t * 32 + tid] = bits;
    }
    // old list (sats of sids(t+1) not in sids(t))
    if (t + 1 < T_STEPS) {
        for (int n = tid; n < NSAT; n += 256) {
            int j = s_ids[(size_t)(t + 1) * NSAT + n];
            if (pos_inv[(size_t)t * GSAT + j] == 0) {
                int slot = atomicAdd(&old_cnt[t], 1);
                short e = (short)(-(j + 1));
                if (t > 0) {
                    int p = (int)pos_inv[(size_t)(t - 1) * GSAT + j] - 1;
                    if (p >= 0) e = (short)p;
                }
                old_src[(size_t)t * NSAT + slot] = e;
            }
        }
    }
    // leave list (rows of sids(t-1) not in sids(t))
    if (t > 0) {
        for (int n = tid; n < NSAT; n += 256) {
            int j = s_ids[(size_t)(t - 1) * NSAT + n];
            if (pos_inv[(size_t)t * GSAT + j] == 0) {
                int slot = atomicAdd(&lv_cnt[t], 1);
                lv[(size_t)t * NSAT + slot] = (n << 16) | j;
            }
        }
    }
}

// transpose [4][256][256] (g,h,o) -> (g,o,h), bf16 output
__global__ void k_wtb(const float* __restrict__ in, ushort_t* __restrict__ outT) {
    __shared__ float tl[32][33];
    int g = blockIdx.z;
    int h0 = blockIdx.x * 32, o0 = blockIdx.y * 32;
    int lx = threadIdx.x & 31, ly = threadIdx.x >> 5;
#pragma unroll
    for (int i = 0; i < 32; i += 8)
        tl[ly + i][lx] = in[((size_t)g * 256 + h0 + ly + i) * 256 + o0 + lx];
    __syncthreads();
#pragma unroll
    for (int i = 0; i < 32; i += 8)
        outT[((size_t)g * 256 + o0 + ly + i) * 256 + h0 + lx] = f2bf(tl[lx][ly + i]);
}

__global__ void k_wrt(const float* __restrict__ W_rec, float* __restrict__ W_recT) {
    int idx = blockIdx.x * 256 + threadIdx.x;
    int g = idx >> 8, o = idx & 255;
#pragma unroll
    for (int i = 0; i < 32; i++)
        W_recT[(size_t)idx * 32 + i] = W_rec[((size_t)g * 32 + i) * 256 + o];
}

// ---------------- per-step kernel: grid 288 (256 sat + 32 rec), no cross-block waits
__launch_bounds__(256)
__global__ void k_step(int t,
    const float* __restrict__ x_rec, const float* __restrict__ x_sat,
    const float* __restrict__ b_rec, const float* __restrict__ s2r_lb,
    const int* __restrict__ asrc, const unsigned* __restrict__ nxt_bits,
    const short* __restrict__ old_src, const int* __restrict__ old_cnt,
    const int* __restrict__ lv, const int* __restrict__ lv_cnt,
    const ushort_t* __restrict__ BsatT, const ushort_t* __restrict__ rlwT2,
    const float* __restrict__ biasC,
    const ushort_t* __restrict__ s2r_rwT, const ushort_t* __restrict__ s2r_lwT,
    const float* __restrict__ W_recT,
    float* __restrict__ meanN,    // [2][8*256]
    float* __restrict__ oldpart,  // [2][32*256]
    float* __restrict__ crec,     // [2][256]
    float* __restrict__ pre_rec,  // [2][1024]
    float* __restrict__ rlpart,   // [2][32][1024]
    ushort_t* __restrict__ Hg_bf, ushort_t* __restrict__ Cg_bf,
    const ushort_t* __restrict__ HnP, ushort_t* __restrict__ HnC,
    const ushort_t* __restrict__ CnP, ushort_t* __restrict__ CnC)
{
    const int b = blockIdx.x, tid = threadIdx.x;
    const float* preP  = pre_rec + ((t + 1) & 1) * 1024;  // pre_rec(t-1)
    const float* crecP = crec + (t & 1) * 256;            // crec(t-2)

    if (b < 256) {
        // ================= satellite block: by row-group, bxc col-group =========
        const int by = b >> 5, bxc = b & 31;
        __shared__ float rl_s[32];
        __shared__ float pre_s[128][33];

        const int w = tid >> 6, l = tid & 63;
        const int lr = l & 15, kb = (l >> 4) * 8;
        const int r0 = w * 32 + lr, r1 = r0 + 16;
        const int* asrc_t = asrc + (size_t)t * NSAT + by * 128;

        // ---- entry: issue ALL independent loads ----
        const int e0 = asrc_t[r0], e1 = asrc_t[r1];
        const int n_ep = tid >> 1, oi0_ep = (tid & 1) * 4;
        const int og0_ep = bxc * 8 + oi0_ep;
        const int en_ep = asrc_t[n_ep];
        const ushort_t* csrc = (en_ep < 1024) ? CnP + (size_t)en_ep * HID + og0_ep
                                              : Cg_bf + (size_t)(en_ep - 1024) * HID + og0_ep;
        s16x4 cold4 = *(const s16x4*)csrc;
        const int gr_ep = by * 128 + n_ep;
        const bool nxt = (t + 1 < T_STEPS) &&
                         ((nxt_bits[t * 32 + (gr_ep >> 5)] >> (gr_ep & 31)) & 1u);
        // lazy-park preload (rows leaving the visible set)
        const int lv_m = lv_cnt[t];
        ushort_t pH[4], pC[4]; int pJ[4];
#pragma unroll
        for (int i = 0; i < 4; i++) {
            int k = b + i * 256;
            if (k < lv_m) {
                int pv = lv[(size_t)t * NSAT + k];
                int pos = pv >> 16; pJ[i] = pv & 0xffff;
                pH[i] = HnP[(size_t)pos * HID + tid];
                pC[i] = CnP[(size_t)pos * HID + tid];
            } else pJ[i] = -1;
        }

        // --- MFMA GEMM: 128 rows x 32 gate-cols, K = 256(h) + 32(x) ---
        const ushort_t* a0 = (e0 < 1024) ? HnP + (size_t)e0 * HID : Hg_bf + (size_t)(e0 - 1024) * HID;
        const ushort_t* a1 = (e1 < 1024) ? HnP + (size_t)e1 * HID : Hg_bf + (size_t)(e1 - 1024) * HID;
        const ushort_t* bp0 = BsatT + ((size_t)(bxc * 32 + lr)) * KTOT;
        const ushort_t* bp1 = bp0 + (size_t)16 * KTOT;
        f32x4 a00 = {0.f,0.f,0.f,0.f}, a01 = a00, a10 = a00, a11 = a00;
#pragma unroll
        for (int kc = 0; kc < 8; kc++) {
            int k0 = kc * 32 + kb;
            s16x8 af0 = *(const s16x8*)(a0 + k0);
            s16x8 af1 = *(const s16x8*)(a1 + k0);
            s16x8 bv0 = *(const s16x8*)(bp0 + k0);
            s16x8 bv1 = *(const s16x8*)(bp1 + k0);
            a00 = __builtin_amdgcn_mfma_f32_16x16x32_bf16(af0, bv0, a00, 0, 0, 0);
            a01 = __builtin_amdgcn_mfma_f32_16x16x32_bf16(af0, bv1, a01, 0, 0, 0);
            a10 = __builtin_amdgcn_mfma_f32_16x16x32_bf16(af1, bv0, a10, 0, 0, 0);
            a11 = __builtin_amdgcn_mfma_f32_16x16x32_bf16(af1, bv1, a11, 0, 0, 0);
        }
        {   // x segment (K = 256..287)
            const float* ax0 = x_sat + ((size_t)t * NSAT + by * 128 + r0) * IN_DIM + kb;
            const float* ax1 = x_sat + ((size_t)t * NSAT + by * 128 + r1) * IN_DIM + kb;
            f32x4 x00 = *(const f32x4*)ax0, x01 = *(const f32x4*)(ax0 + 4);
            f32x4 x10 = *(const f32x4*)ax1, x11 = *(const f32x4*)(ax1 + 4);
            s16x8 af0, af1;
#pragma unroll
            for (int e = 0; e < 4; e++) {
                af0[e] = (short)f2bf(x00[e]); af0[4 + e] = (short)f2bf(x01[e]);
                af1[e] = (short)f2bf(x10[e]); af1[4 + e] = (short)f2bf(x11[e]);
            }
            int k0 = 256 + kb;
            s16x8 bv0 = *(const s16x8*)(bp0 + k0);
            s16x8 bv1 = *(const s16x8*)(bp1 + k0);
            a00 = __builtin_amdgcn_mfma_f32_16x16x32_bf16(af0, bv0, a00, 0, 0, 0);
            a01 = __builtin_amdgcn_mfma_f32_16x16x32_bf16(af0, bv1, a01, 0, 0, 0);
            a10 = __builtin_amdgcn_mfma_f32_16x16x32_bf16(af1, bv0, a10, 0, 0, 0);
            a11 = __builtin_amdgcn_mfma_f32_16x16x32_bf16(af1, bv1, a11, 0, 0, 0);
        }

        // --- rl: sum 32 rec-side partials (prev launch) + bias; no LDS input dep ---
        {
            int c = tid >> 3, sub = tid & 7;
            const float* rp = rlpart + (size_t)(t & 1) * 32768 + bxc * 32 + c;
            float part = rp[(size_t)(sub * 4 + 0) * 1024]
                       + rp[(size_t)(sub * 4 + 1) * 1024]
                       + rp[(size_t)(sub * 4 + 2) * 1024]
                       + rp[(size_t)(sub * 4 + 3) * 1024];
            part += __shfl_down(part, 4, 8);
            part += __shfl_down(part, 2, 8);
            part += __shfl_down(part, 1, 8);
            if (sub == 0) rl_s[c] = part + biasC[bxc * 32 + c];
        }
        // stage C (col=lane&15, row=(lane>>4)*4+reg)
#pragma unroll
        for (int rr = 0; rr < 4; rr++) {
            int ro = (l >> 4) * 4 + rr;
            pre_s[w * 32 + ro][lr]           = a00[rr];
            pre_s[w * 32 + ro][16 + lr]      = a01[rr];
            pre_s[w * 32 + 16 + ro][lr]      = a10[rr];
            pre_s[w * 32 + 16 + ro][16 + lr] = a11[rr];
        }
        __syncthreads();   // publish pre_s + rl_s (single pre-epilogue barrier)

        // --- epilogue: LSTM over 4 cells/thread (cold-C preloaded, bf16) ---
        {
            int n = n_ep, oi0 = oi0_ep, og0 = og0_ep;
            f32x4 hf; s16x4 cnew, hnew;
#pragma unroll
            for (int e = 0; e < 4; e++) {
                int oi = oi0 + e;
                float pi = pre_s[n][oi]      + rl_s[oi];
                float pf = pre_s[n][8 + oi]  + rl_s[8 + oi];
                float pc = pre_s[n][16 + oi] + rl_s[16 + oi];
                float po = pre_s[n][24 + oi] + rl_s[24 + oi];
                float ig = sigm(pi), fg = sigm(pf), tg = tanh_(pc), oo = sigm(po);
                float cn = fg * bf2f((ushort_t)cold4[e]) + ig * tg;
                float hn = oo * tanh_(cn);
                hf[e] = hn;
                cnew[e] = (short)f2bf(cn);
                hnew[e] = (short)f2bf(hn);
            }
            *(s16x4*)(CnC + (size_t)gr_ep * HID + og0) = cnew;
            *(s16x4*)(HnC + (size_t)gr_ep * HID + og0) = hnew;
#pragma unroll
            for (int e = 0; e < 4; e++) pre_s[n_ep][oi0 + e] = nxt ? hf[e] : 0.f;
        }
        __syncthreads();
        // --- meanN: parallel reduce, 8 col-groups x 32 lanes ---
        if (t + 1 < T_STEPS) {
            int c = tid >> 5, lane = tid & 31;
            float s = pre_s[lane][c] + pre_s[lane + 32][c]
                    + pre_s[lane + 64][c] + pre_s[lane + 96][c];
            s += __shfl_down(s, 16, 32);
            s += __shfl_down(s, 8, 32);
            s += __shfl_down(s, 4, 32);
            s += __shfl_down(s, 2, 32);
            s += __shfl_down(s, 1, 32);
            if (lane == 0)
                meanN[((t + 1) & 1) * 2048 + by * 256 + bxc * 8 + c] = s;
        }

        // --- lazy park of departing rows (values preloaded at entry) ---
#pragma unroll
        for (int i = 0; i < 4; i++) {
            if (pJ[i] >= 0) {
                Hg_bf[(size_t)pJ[i] * HID + tid] = pH[i];
                Cg_bf[(size_t)pJ[i] * HID + tid] = pC[i];
            }
        }
    } else {
        // ============ rec block r: mean -> pre_rec(t) -> cell -> rlpart(t+1) ======
        const int r = b - 256;
        __shared__ float mean_s[256], hr_s[256], xr_s[32], pre4[4][8], hn_s[8];
        const int m_old = (t + 1 < T_STEPS) ? old_cnt[t] : 0;   // issued first
        {   // reduce mean(t) from prev-launch partials
            float s = 0.f;
            const float* mp = meanN + (t & 1) * 2048;
#pragma unroll
            for (int p = 0; p < 8; p++) s += mp[p * 256 + tid];
            const float* op = oldpart + (t & 1) * 8192;
#pragma unroll 8
            for (int p = 0; p < 32; p++) s += op[p * 256 + tid];
            mean_s[tid] = s * (1.f / 1024.f);
        }
        float cn_prev = 0.f;
        {   // elementwise h_rec(t-1); r==0 stores crec(t-1); keep cn in reg
            float h = 0.f;
            if (t > 0) {
                float pi = preP[tid], pf = preP[256 + tid], pc = preP[512 + tid], po = preP[768 + tid];
                float cp = (t >= 2) ? crecP[tid] : 0.f;
                cn_prev = sigm(pf) * cp + sigm(pi) * tanh_(pc);
                h = sigm(po) * tanh_(cn_prev);
            }
            hr_s[tid] = h;
            if (r == 0 && t > 0) crec[((t + 1) & 1) * 256 + tid] = cn_prev;
        }
        if (tid < 32) xr_s[tid] = x_rec[(size_t)t * IN_DIM + tid];
        __syncthreads();
        // oldpart(t+1) gather issued BEFORE the matvec: latency hides under it
        float s_old = 0.f;
        {
            const short* osp = old_src + (size_t)t * NSAT;
#pragma unroll 2
            for (int k = r; k < m_old; k += 32) {
                int e = osp[k];
                const ushort_t* hp = (e >= 0) ? HnP + (size_t)e * HID
                                              : Hg_bf + (size_t)(-(e + 1)) * HID;
                s_old += bf2f(hp[tid]);
            }
        }
        {   // pre_rec(t) matvec: 32 gate-outs per block (bf16 weights)
            const int combo = tid >> 3, sub = tid & 7;
            const int g = combo >> 3, oo = combo & 7;
            const int o = r * 8 + oo;
            const ushort_t* rwp = s2r_rwT + ((size_t)(g * 256 + o)) * 256 + sub * 32;
            const ushort_t* lwp = s2r_lwT + ((size_t)(g * 256 + o)) * 256 + sub * 32;
            float part = 0.f;
#pragma unroll
            for (int q = 0; q < 4; q++) {
                s16x8 a = *(const s16x8*)(rwp + q * 8);
                s16x8 c = *(const s16x8*)(lwp + q * 8);
#pragma unroll
                for (int e = 0; e < 8; e++) {
                    int h = sub * 32 + q * 8 + e;
                    part += hr_s[h] * bf2f((ushort_t)a[e]) + mean_s[h] * bf2f((ushort_t)c[e]);
                }
            }
            {
                f32x4 wx = *(const f32x4*)(W_recT + ((size_t)(g * 256 + o)) * 32 + sub * 4);
#pragma unroll
                for (int e = 0; e < 4; e++) part += xr_s[sub * 4 + e] * wx[e];
            }
            part += __shfl_down(part, 4);
            part += __shfl_down(part, 2);
            part += __shfl_down(part, 1);
            if (sub == 0) {
                float pv = part + b_rec[g * HID + o] + s2r_lb[g * HID + o];
                pre_rec[(t & 1) * 1024 + g * 256 + o] = pv;
                pre4[g][oo] = pv;
            }
        }
        if (t + 1 < T_STEPS)
            oldpart[((t + 1) & 1) * 8192 + r * 256 + tid] = s_old;
        __syncthreads();
        // cell update for this block's 8 h-elems (thread tid == o2 holds cn_prev[o2])
        if (tid >= r * 8 && tid < r * 8 + 8) {
            int oo = tid - r * 8;
            float pi = pre4[0][oo], pf = pre4[1][oo], pc = pre4[2][oo], po = pre4[3][oo];
            float cp = (t > 0) ? cn_prev : 0.f;
            float cnn = sigm(pf) * cp + sigm(pi) * tanh_(pc);
            hn_s[oo] = sigm(po) * tanh_(cnn);
        }
        __syncthreads();
        // rlpart(t+1)[r][c] = sum_{h in r's 8} rlw[h][c] * h_rec(t)[h]
        {
            float acc0 = 0.f, acc1 = 0.f, acc2 = 0.f, acc3 = 0.f;
#pragma unroll
            for (int k8 = 0; k8 < 8; k8++) {
                float hv = hn_s[k8];
                s16x4 wv = *(const s16x4*)(rlwT2 + (size_t)(r * 8 + k8) * 1024 + tid * 4);
                acc0 += hv * bf2f((ushort_t)wv[0]);
                acc1 += hv * bf2f((ushort_t)wv[1]);
                acc2 += hv * bf2f((ushort_t)wv[2]);
                acc3 += hv * bf2f((ushort_t)wv[3]);
            }
            float* dst = rlpart + (size_t)((t + 1) & 1) * 32768 + r * 1024 + tid * 4;
            dst[0] = acc0; dst[1] = acc1; dst[2] = acc2; dst[3] = acc3;
        }
    }
}

// ---------------- final: elementwise h_rec(255) + output projection ----------------
__global__ void k_final(const float* __restrict__ pre_rec,
                        const float* __restrict__ crec,
                        const float* __restrict__ W_out,
                        const float* __restrict__ b_out,
                        const float* __restrict__ y_true,
                        float* __restrict__ out) {
    __shared__ float red[256];
    int o = threadIdx.x;
    const float* pre = pre_rec + ((T_STEPS - 1) & 1) * 1024;   // pre_rec(255)
    float pi = pre[o], pf = pre[256 + o], pc = pre[512 + o], po = pre[768 + o];
    float cp = crec[(T_STEPS & 1) * 256 + o];                  // crec(254)
    float cn = sigm(pf) * cp + sigm(pi) * tanh_(pc);
    float h = sigm(po) * tanh_(cn);
    for (int j = 0; j < 2; j++) {
        red[o] = h * W_out[o * 2 + j];
        __syncthreads();
        for (int s = 128; s > 0; s >>= 1) {
            if (o < s) red[o] += red[o + s];
            __syncthreads();
        }
        if (o == 0) out[j] = red[0] + b_out[j];
        __syncthreads();
    }
    if (o < 2) out[2 + o] = y_true[o];
}

extern "C" void kernel_launch(void* const* d_in, const int* in_sizes, int n_in,
                              void* d_out, int out_size, void* d_ws, size_t ws_size,
                              hipStream_t stream) {
    (void)in_sizes; (void)n_in; (void)out_size; (void)ws_size;
    const float* x_rec  = (const float*)d_in[0];
    const float* x_sat  = (const float*)d_in[1];
    const float* y_true = (const float*)d_in[2];
    const float* W_rec  = (const float*)d_in[3];
    const float* b_rec  = (const float*)d_in[4];
    const float* W_sat  = (const float*)d_in[5];
    const float* b_sat  = (const float*)d_in[6];
    const float* s2r_lw = (const float*)d_in[7];
    const float* s2r_lb = (const float*)d_in[8];
    const float* s2r_rw = (const float*)d_in[9];
    const float* r2s_lw = (const float*)d_in[10];
    const float* r2s_lb = (const float*)d_in[11];
    const float* r2s_rw = (const float*)d_in[12];
    const float* W_out  = (const float*)d_in[13];
    const float* b_out  = (const float*)d_in[14];
    const int*   s_ids  = (const int*)d_in[15];

    float* ws = (float*)d_ws;
    size_t off = 0;
    // ---- zeroed prefix ----
    float*    meanN    = ws + off;              off += 4096;    // [2][8*256]
    float*    oldpart  = ws + off;              off += 16384;   // [2][32*256]
    float*    crec     = ws + off;              off += 512;     // [2][256]
    float*    pre_rec  = ws + off;              off += 2048;    // [2][1024]
    int*      old_cnt  = (int*)(ws + off);      off += 256;
    int*      lv_cnt   = (int*)(ws + off);      off += 256;
    float*    rlpart   = ws + off;              off += 65536;   // [2][32][1024]
    ushort_t* Hg_bf    = (ushort_t*)(ws + off); off += 262144;  // 2048*256 u16
    ushort_t* Cg_bf    = (ushort_t*)(ws + off); off += 262144;  // 2048*256 u16
    ushort_t* pos_inv  = (ushort_t*)(ws + off); off += 262144;  // 256*2048 u16
    // ---- zero prefix ends here ----
    int*      asrc     = (int*)(ws + off);      off += 262144;  // [256][1024] int
    unsigned* nxt_bits = (unsigned*)(ws + off); off += 8192;    // [256][32] u32
    short*    old_src  = (short*)(ws + off);    off += 131072;  // [256][1024] s16
    int*      lv       = (int*)(ws + off);      off += 262144;  // [256][1024] int
    ushort_t* HnewA    = (ushort_t*)(ws + off); off += 131072;  // 1024*256 u16
    ushort_t* HnewB    = (ushort_t*)(ws + off); off += 131072;
    ushort_t* CnewA    = (ushort_t*)(ws + off); off += 131072;  // 1024*256 u16
    ushort_t* CnewB    = (ushort_t*)(ws + off); off += 131072;
    ushort_t* BsatT    = (ushort_t*)(ws + off); off += 147456;  // 1024*288 u16
    ushort_t* rlwT2    = (ushort_t*)(ws + off); off += 131072;  // [256][1024] u16
    float*    biasC    = ws + off;              off += 1024;
    ushort_t* s2r_rwT  = (ushort_t*)(ws + off); off += 131072;  // bf16 [4][256][256]
    ushort_t* s2r_lwT  = (ushort_t*)(ws + off); off += 131072;
    float*    W_recT   = ws + off;              off += 32768;   // 4*256*32

    const size_t zcount = 4096 + 16384 + 512 + 2048 + 256 + 256 + 65536
                        + 262144 + 262144 + 262144;
    hipLaunchKernelGGL(k_zero, dim3(2048), dim3(256), 0, stream, ws, zcount);
    hipLaunchKernelGGL(k_inv, dim3(T_STEPS), dim3(256), 0, stream, s_ids, pos_inv);
    hipLaunchKernelGGL(k_idx, dim3(T_STEPS), dim3(256), 0, stream, s_ids, pos_inv,
                       asrc, nxt_bits, old_src, old_cnt, lv, lv_cnt);
    hipLaunchKernelGGL(k_bconv, dim3(1024), dim3(256), 0, stream, r2s_rw, W_sat, BsatT);
    hipLaunchKernelGGL(k_rlw2, dim3(256), dim3(256), 0, stream, r2s_lw, rlwT2);
    hipLaunchKernelGGL(k_biasC, dim3(4), dim3(256), 0, stream, r2s_lb, b_sat, biasC);
    hipLaunchKernelGGL(k_wtb, dim3(8, 8, 4), dim3(256), 0, stream, s2r_rw, s2r_rwT);
    hipLaunchKernelGGL(k_wtb, dim3(8, 8, 4), dim3(256), 0, stream, s2r_lw, s2r_lwT);
    hipLaunchKernelGGL(k_wrt, dim3(4), dim3(256), 0, stream, W_rec, W_recT);

    for (int t = 0; t < T_STEPS; t++) {
        const ushort_t* HnP = (t & 1) ? HnewA : HnewB;
        ushort_t*       HnC = (t & 1) ? HnewB : HnewA;
        const ushort_t* CnP = (t & 1) ? CnewA : CnewB;
        ushort_t*       CnC = (t & 1) ? CnewB : CnewA;
        hipLaunchKernelGGL(k_step, dim3(288), dim3(256), 0, stream,
                           t, x_rec, x_sat, b_rec, s2r_lb,
                           asrc, nxt_bits, old_src, old_cnt, lv, lv_cnt,
                           BsatT, rlwT2, biasC,
                           s2r_rwT, s2r_lwT, W_recT,
                           meanN, oldpart, crec, pre_rec, rlpart,
                           Hg_bf, Cg_bf, HnP, HnC, CnP, CnC);
    }
    hipLaunchKernelGGL(k_final, dim3(1), dim3(256), 0, stream,
                       pre_rec, crec, W_out, b_out, y_true, (float*)d_out);
}

// Round 12
// 3458.396 us; speedup vs baseline: 1.0454x; 1.0454x over previous
//
#include <hip/hip_runtime.h>
#include <cstddef>

#define T_STEPS  256
#define NSAT     1024
#define GSAT     2048
#define HID      256
#define IN_DIM   32
#define KTOT     288   // 256 h_sat + 32 x_sat

typedef short  s16x8 __attribute__((ext_vector_type(8)));
typedef short  s16x4 __attribute__((ext_vector_type(4)));
typedef float  f32x4 __attribute__((ext_vector_type(4)));
typedef unsigned short ushort_t;

__device__ inline ushort_t f2bf(float f) {
    unsigned u = __builtin_bit_cast(unsigned, f);
    u += 0x7fffu + ((u >> 16) & 1u);
    return (ushort_t)(u >> 16);
}
__device__ inline float bf2f(ushort_t h) {
    unsigned u = ((unsigned)h) << 16;
    return __builtin_bit_cast(float, u);
}
__device__ inline float sigm(float x) { return 1.f / (1.f + __expf(-x)); }
__device__ inline float tanh_(float x) {
    float a = fabsf(x);
    float e = __expf(-2.f * a);
    float r = (1.f - e) / (1.f + e);
    return copysignf(r, x);
}

// ---------------- init: zero prefix ----------------
__global__ void k_zero(float* p, size_t n) {
    size_t i = (size_t)blockIdx.x * blockDim.x + threadIdx.x;
    size_t stride = (size_t)gridDim.x * blockDim.x;
    for (; i < n; i += stride) p[i] = 0.f;
}

// col order: c = (o>>3)*32 + g*8 + (o&7)  <->  g=(c>>3)&3, o=(c>>5)*8+(c&7)
__global__ void k_bconv(const float* __restrict__ r2s_rw,
                        const float* __restrict__ W_sat,
                        ushort_t* __restrict__ BsatT) {
    int c = blockIdx.x;
    int g = (c >> 3) & 3, o = (c >> 5) * 8 + (c & 7);
    for (int k = threadIdx.x; k < KTOT; k += 256) {
        float v = (k < 256) ? r2s_rw[((size_t)g * 256 + k) * 256 + o]
                            : W_sat[((size_t)g * 32 + (k - 256)) * 256 + o];
        BsatT[(size_t)c * KTOT + k] = f2bf(v);
    }
}

// rlw_bf[c][h] = r2s_lw[g][h][o], bf16 (col-major for in-sat rl matvec)
__global__ void k_rlw(const float* __restrict__ r2s_lw, ushort_t* __restrict__ rlw_bf) {
    int c = blockIdx.x;
    int g = (c >> 3) & 3, o = (c >> 5) * 8 + (c & 7);
    int h = threadIdx.x;
    rlw_bf[(size_t)c * 256 + h] = f2bf(r2s_lw[((size_t)g * 256 + h) * 256 + o]);
}

__global__ void k_biasC(const float* __restrict__ r2s_lb, const float* __restrict__ b_sat,
                        float* __restrict__ biasC) {
    int c = blockIdx.x * 256 + threadIdx.x;
    if (c < 1024) {
        int g = (c >> 3) & 3, o = (c >> 5) * 8 + (c & 7);
        biasC[c] = r2s_lb[g * 256 + o] + b_sat[g * 256 + o];
    }
}

__global__ void k_inv(const int* __restrict__ s_ids, ushort_t* __restrict__ pos_inv) {
    int t = blockIdx.x;
    for (int n = threadIdx.x; n < NSAT; n += 256)
        pos_inv[(size_t)t * GSAT + s_ids[(size_t)t * NSAT + n]] = (ushort_t)(n + 1);
}

// merged index precompute: asrc, nxt_bits, old list, leave list (per t)
__global__ void k_idx(const int* __restrict__ s_ids, const ushort_t* __restrict__ pos_inv,
                      int* __restrict__ asrc, unsigned* __restrict__ nxt_bits,
                      short* __restrict__ old_src, int* __restrict__ old_cnt,
                      int* __restrict__ lv, int* __restrict__ lv_cnt) {
    int t = blockIdx.x, tid = threadIdx.x;
    for (int n = tid; n < NSAT; n += 256) {
        int j = s_ids[(size_t)t * NSAT + n];
        int e = 1024 + j;
        if (t > 0) {
            int p = (int)pos_inv[(size_t)(t - 1) * GSAT + j] - 1;
            if (p >= 0) e = p;
        }
        asrc[(size_t)t * NSAT + n] = e;
    }
    if (tid < 32) {
        unsigned bits = 0;
        if (t + 1 < T_STEPS) {
            for (int i = 0; i < 32; i++) {
                int j = s_ids[(size_t)t * NSAT + tid * 32 + i];
                if (pos_inv[(size_t)(t + 1) * GSAT + j] > 0) bits |= (1u << i);
            }
        }
        nxt_bits[t * 32 + tid] = bits;
    }
    if (t + 1 < T_STEPS) {
        for (int n = tid; n < NSAT; n += 256) {
            int j = s_ids[(size_t)(t + 1) * NSAT + n];
            if (pos_inv[(size_t)t * GSAT + j] == 0) {
                int slot = atomicAdd(&old_cnt[t], 1);
                short e = (short)(-(j + 1));
                if (t > 0) {
                    int p = (int)pos_inv[(size_t)(t - 1) * GSAT + j] - 1;
                    if (p >= 0) e = (short)p;
                }
                old_src[(size_t)t * NSAT + slot] = e;
            }
        }
    }
    if (t > 0) {
        for (int n = tid; n < NSAT; n += 256) {
            int j = s_ids[(size_t)(t - 1) * NSAT + n];
            if (pos_inv[(size_t)t * GSAT + j] == 0) {
                int slot = atomicAdd(&lv_cnt[t], 1);
                lv[(size_t)t * NSAT + slot] = (n << 16) | j;
            }
        }
    }
}

// transpose [4][256][256] (g,h,o) -> (g,o,h), bf16 output
__global__ void k_wtb(const float* __restrict__ in, ushort_t* __restrict__ outT) {
    __shared__ float tl[32][33];
    int g = blockIdx.z;
    int h0 = blockIdx.x * 32, o0 = blockIdx.y * 32;
    int lx = threadIdx.x & 31, ly = threadIdx.x >> 5;
#pragma unroll
    for (int i = 0; i < 32; i += 8)
        tl[ly + i][lx] = in[((size_t)g * 256 + h0 + ly + i) * 256 + o0 + lx];
    __syncthreads();
#pragma unroll
    for (int i = 0; i < 32; i += 8)
        outT[((size_t)g * 256 + o0 + ly + i) * 256 + h0 + lx] = f2bf(tl[lx][ly + i]);
}

__global__ void k_wrt(const float* __restrict__ W_rec, float* __restrict__ W_recT) {
    int idx = blockIdx.x * 256 + threadIdx.x;
    int g = idx >> 8, o = idx & 255;
#pragma unroll
    for (int i = 0; i < 32; i++)
        W_recT[(size_t)idx * 32 + i] = W_rec[((size_t)g * 32 + i) * 256 + o];
}

// ---------------- per-step kernel: grid 288 (256 sat + 32 rec), no cross-block waits
__launch_bounds__(256)
__global__ void k_step(int t,
    const float* __restrict__ x_rec, const float* __restrict__ x_sat,
    const float* __restrict__ b_rec, const float* __restrict__ s2r_lb,
    const int* __restrict__ asrc, const unsigned* __restrict__ nxt_bits,
    const short* __restrict__ old_src, const int* __restrict__ old_cnt,
    const int* __restrict__ lv, const int* __restrict__ lv_cnt,
    const ushort_t* __restrict__ BsatT, const ushort_t* __restrict__ rlw_bf,
    const float* __restrict__ biasC,
    const ushort_t* __restrict__ s2r_rwT, const ushort_t* __restrict__ s2r_lwT,
    const float* __restrict__ W_recT,
    float* __restrict__ meanN,    // [2][8*256]
    float* __restrict__ oldpart,  // [2][32*256]
    float* __restrict__ crec,     // [2][256]
    float* __restrict__ pre_rec,  // [2][1024]
    ushort_t* __restrict__ Hg_bf, ushort_t* __restrict__ Cg_bf,
    const ushort_t* __restrict__ HnP, ushort_t* __restrict__ HnC,
    const ushort_t* __restrict__ CnP, ushort_t* __restrict__ CnC)
{
    const int b = blockIdx.x, tid = threadIdx.x;
    const float* preP  = pre_rec + ((t + 1) & 1) * 1024;  // pre_rec(t-1)
    const float* crecP = crec + (t & 1) * 256;            // crec(t-2)

    if (b < 256) {
        // ================= satellite block: by row-group, bxc col-group =========
        const int by = b >> 5, bxc = b & 31;
        __shared__ ushort_t hr_bfs[256];
        __shared__ float    bias_s[32];
        __shared__ float    rl_s[32];
        __shared__ float    pre_s[128][33];

        const int w = tid >> 6, l = tid & 63;
        const int lr = l & 15, kb = (l >> 4) * 8;
        const int r0 = w * 32 + lr, r1 = r0 + 16;
        const int* asrc_t = asrc + (size_t)t * NSAT + by * 128;

        // ---- entry: issue ALL independent loads ----
        const int e0 = asrc_t[r0], e1 = asrc_t[r1];
        if (tid < 32) bias_s[tid] = biasC[bxc * 32 + tid];
        const int n_ep = tid >> 1, oi0_ep = (tid & 1) * 4;
        const int og0_ep = bxc * 8 + oi0_ep;
        const int en_ep = asrc_t[n_ep];
        const ushort_t* csrc = (en_ep < 1024) ? CnP + (size_t)en_ep * HID + og0_ep
                                              : Cg_bf + (size_t)(en_ep - 1024) * HID + og0_ep;
        s16x4 cold4 = *(const s16x4*)csrc;
        const int gr_ep = by * 128 + n_ep;
        const bool nxt = (t + 1 < T_STEPS) &&
                         ((nxt_bits[t * 32 + (gr_ep >> 5)] >> (gr_ep & 31)) & 1u);
        // lazy-park preload (rows leaving the visible set)
        const int lv_m = lv_cnt[t];
        ushort_t pH[4], pC[4]; int pJ[4];
#pragma unroll
        for (int i = 0; i < 4; i++) {
            int k = b + i * 256;
            if (k < lv_m) {
                int pv = lv[(size_t)t * NSAT + k];
                int pos = pv >> 16; pJ[i] = pv & 0xffff;
                pH[i] = HnP[(size_t)pos * HID + tid];
                pC[i] = CnP[(size_t)pos * HID + tid];
            } else pJ[i] = -1;
        }
        // h_rec(t-1) recompute
        {
            float h = 0.f;
            if (t > 0) {
                float pi = preP[tid], pf = preP[256 + tid], pc = preP[512 + tid], po = preP[768 + tid];
                float cp = (t >= 2) ? crecP[tid] : 0.f;
                float cn = sigm(pf) * cp + sigm(pi) * tanh_(pc);
                h = sigm(po) * tanh_(cn);
            }
            hr_bfs[tid] = f2bf(h);
        }
        __syncthreads();   // publish hr_bfs + bias_s (early; GEMM A-gathers still in flight)

        // --- rl matvec BEFORE the GEMM: overlaps the A-row gather latency ---
        {
            int c = tid >> 3, sub = tid & 7;
            const ushort_t* wp = rlw_bf + ((size_t)(bxc * 32 + c)) * 256 + sub * 32;
            float acc = 0.f;
#pragma unroll
            for (int q = 0; q < 4; q++) {
                s16x8 wv = *(const s16x8*)(wp + q * 8);
#pragma unroll
                for (int e = 0; e < 8; e++)
                    acc += bf2f(hr_bfs[sub * 32 + q * 8 + e]) * bf2f((ushort_t)wv[e]);
            }
            acc += __shfl_down(acc, 4, 8);
            acc += __shfl_down(acc, 2, 8);
            acc += __shfl_down(acc, 1, 8);
            if (sub == 0) rl_s[c] = acc + bias_s[c];
        }

        // --- MFMA GEMM: 128 rows x 32 gate-cols, K = 256(h) + 32(x) ---
        const ushort_t* a0 = (e0 < 1024) ? HnP + (size_t)e0 * HID : Hg_bf + (size_t)(e0 - 1024) * HID;
        const ushort_t* a1 = (e1 < 1024) ? HnP + (size_t)e1 * HID : Hg_bf + (size_t)(e1 - 1024) * HID;
        const ushort_t* bp0 = BsatT + ((size_t)(bxc * 32 + lr)) * KTOT;
        const ushort_t* bp1 = bp0 + (size_t)16 * KTOT;
        f32x4 a00 = {0.f,0.f,0.f,0.f}, a01 = a00, a10 = a00, a11 = a00;
#pragma unroll
        for (int kc = 0; kc < 8; kc++) {
            int k0 = kc * 32 + kb;
            s16x8 af0 = *(const s16x8*)(a0 + k0);
            s16x8 af1 = *(const s16x8*)(a1 + k0);
            s16x8 bv0 = *(const s16x8*)(bp0 + k0);
            s16x8 bv1 = *(const s16x8*)(bp1 + k0);
            a00 = __builtin_amdgcn_mfma_f32_16x16x32_bf16(af0, bv0, a00, 0, 0, 0);
            a01 = __builtin_amdgcn_mfma_f32_16x16x32_bf16(af0, bv1, a01, 0, 0, 0);
            a10 = __builtin_amdgcn_mfma_f32_16x16x32_bf16(af1, bv0, a10, 0, 0, 0);
            a11 = __builtin_amdgcn_mfma_f32_16x16x32_bf16(af1, bv1, a11, 0, 0, 0);
        }
        {   // x segment (K = 256..287)
            const float* ax0 = x_sat + ((size_t)t * NSAT + by * 128 + r0) * IN_DIM + kb;
            const float* ax1 = x_sat + ((size_t)t * NSAT + by * 128 + r1) * IN_DIM + kb;
            f32x4 x00 = *(const f32x4*)ax0, x01 = *(const f32x4*)(ax0 + 4);
            f32x4 x10 = *(const f32x4*)ax1, x11 = *(const f32x4*)(ax1 + 4);
            s16x8 af0, af1;
#pragma unroll
            for (int e = 0; e < 4; e++) {
                af0[e] = (short)f2bf(x00[e]); af0[4 + e] = (short)f2bf(x01[e]);
                af1[e] = (short)f2bf(x10[e]); af1[4 + e] = (short)f2bf(x11[e]);
            }
            int k0 = 256 + kb;
            s16x8 bv0 = *(const s16x8*)(bp0 + k0);
            s16x8 bv1 = *(const s16x8*)(bp1 + k0);
            a00 = __builtin_amdgcn_mfma_f32_16x16x32_bf16(af0, bv0, a00, 0, 0, 0);
            a01 = __builtin_amdgcn_mfma_f32_16x16x32_bf16(af0, bv1, a01, 0, 0, 0);
            a10 = __builtin_amdgcn_mfma_f32_16x16x32_bf16(af1, bv0, a10, 0, 0, 0);
            a11 = __builtin_amdgcn_mfma_f32_16x16x32_bf16(af1, bv1, a11, 0, 0, 0);
        }
        // stage C (col=lane&15, row=(lane>>4)*4+reg)
#pragma unroll
        for (int rr = 0; rr < 4; rr++) {
            int ro = (l >> 4) * 4 + rr;
            pre_s[w * 32 + ro][lr]           = a00[rr];
            pre_s[w * 32 + ro][16 + lr]      = a01[rr];
            pre_s[w * 32 + 16 + ro][lr]      = a10[rr];
            pre_s[w * 32 + 16 + ro][16 + lr] = a11[rr];
        }
        __syncthreads();   // publish pre_s + rl_s

        // --- epilogue: LSTM over 4 cells/thread (cold-C preloaded, bf16) ---
        {
            int n = n_ep, oi0 = oi0_ep, og0 = og0_ep;
            f32x4 hf; s16x4 cnew, hnew;
#pragma unroll
            for (int e = 0; e < 4; e++) {
                int oi = oi0 + e;
                float pi = pre_s[n][oi]      + rl_s[oi];
                float pf = pre_s[n][8 + oi]  + rl_s[8 + oi];
                float pc = pre_s[n][16 + oi] + rl_s[16 + oi];
                float po = pre_s[n][24 + oi] + rl_s[24 + oi];
                float ig = sigm(pi), fg = sigm(pf), tg = tanh_(pc), oo = sigm(po);
                float cn = fg * bf2f((ushort_t)cold4[e]) + ig * tg;
                float hn = oo * tanh_(cn);
                hf[e] = hn;
                cnew[e] = (short)f2bf(cn);
                hnew[e] = (short)f2bf(hn);
            }
            *(s16x4*)(CnC + (size_t)gr_ep * HID + og0) = cnew;
            *(s16x4*)(HnC + (size_t)gr_ep * HID + og0) = hnew;
#pragma unroll
            for (int e = 0; e < 4; e++) pre_s[n_ep][oi0 + e] = nxt ? hf[e] : 0.f;
        }
        __syncthreads();
        // --- meanN: parallel reduce, 8 col-groups x 32 lanes ---
        if (t + 1 < T_STEPS) {
            int c = tid >> 5, lane = tid & 31;
            float s = pre_s[lane][c] + pre_s[lane + 32][c]
                    + pre_s[lane + 64][c] + pre_s[lane + 96][c];
            s += __shfl_down(s, 16, 32);
            s += __shfl_down(s, 8, 32);
            s += __shfl_down(s, 4, 32);
            s += __shfl_down(s, 2, 32);
            s += __shfl_down(s, 1, 32);
            if (lane == 0)
                meanN[((t + 1) & 1) * 2048 + by * 256 + bxc * 8 + c] = s;
        }

        // --- lazy park of departing rows (values preloaded at entry) ---
#pragma unroll
        for (int i = 0; i < 4; i++) {
            if (pJ[i] >= 0) {
                Hg_bf[(size_t)pJ[i] * HID + tid] = pH[i];
                Cg_bf[(size_t)pJ[i] * HID + tid] = pC[i];
            }
        }
    } else {
        // ================= rec block r: mean reduce -> oldpart(t+1) -> pre_rec(t) ==
        const int r = b - 256;
        __shared__ float mean_s[256], hr_s[256], xr_s[32];
        const int m_old = (t + 1 < T_STEPS) ? old_cnt[t] : 0;   // issued first
        {   // reduce mean(t) from prev-launch partials
            float s = 0.f;
            const float* mp = meanN + (t & 1) * 2048;
#pragma unroll
            for (int p = 0; p < 8; p++) s += mp[p * 256 + tid];
            const float* op = oldpart + (t & 1) * 8192;
#pragma unroll 8
            for (int p = 0; p < 32; p++) s += op[p * 256 + tid];
            mean_s[tid] = s * (1.f / 1024.f);
        }
        {   // elementwise h_rec(t-1); block r==0 stores crec(t-1)
            float h = 0.f, cn = 0.f;
            if (t > 0) {
                float pi = preP[tid], pf = preP[256 + tid], pc = preP[512 + tid], po = preP[768 + tid];
                float cp = (t >= 2) ? crecP[tid] : 0.f;
                cn = sigm(pf) * cp + sigm(pi) * tanh_(pc);
                h = sigm(po) * tanh_(cn);
            }
            hr_s[tid] = h;
            if (r == 0 && t > 0) crec[((t + 1) & 1) * 256 + tid] = cn;
        }
        if (tid < 32) xr_s[tid] = x_rec[(size_t)t * IN_DIM + tid];
        __syncthreads();
        // oldpart(t+1) gather issued BEFORE the matvec: latency hides under it
        float s_old = 0.f;
        {
            const short* osp = old_src + (size_t)t * NSAT;
#pragma unroll 2
            for (int k = r; k < m_old; k += 32) {
                int e = osp[k];
                const ushort_t* hp = (e >= 0) ? HnP + (size_t)e * HID
                                              : Hg_bf + (size_t)(-(e + 1)) * HID;
                s_old += bf2f(hp[tid]);
            }
        }
        {   // pre_rec(t) matvec: 32 gate-outs per block (bf16 weights)
            const int combo = tid >> 3, sub = tid & 7;
            const int g = combo >> 3, oo = combo & 7;
            const int o = r * 8 + oo;
            const ushort_t* rwp = s2r_rwT + ((size_t)(g * 256 + o)) * 256 + sub * 32;
            const ushort_t* lwp = s2r_lwT + ((size_t)(g * 256 + o)) * 256 + sub * 32;
            float part = 0.f;
#pragma unroll
            for (int q = 0; q < 4; q++) {
                s16x8 a = *(const s16x8*)(rwp + q * 8);
                s16x8 c = *(const s16x8*)(lwp + q * 8);
#pragma unroll
                for (int e = 0; e < 8; e++) {
                    int h = sub * 32 + q * 8 + e;
                    part += hr_s[h] * bf2f((ushort_t)a[e]) + mean_s[h] * bf2f((ushort_t)c[e]);
                }
            }
            {
                f32x4 wx = *(const f32x4*)(W_recT + ((size_t)(g * 256 + o)) * 32 + sub * 4);
#pragma unroll
                for (int e = 0; e < 4; e++) part += xr_s[sub * 4 + e] * wx[e];
            }
            part += __shfl_down(part, 4);
            part += __shfl_down(part, 2);
            part += __shfl_down(part, 1);
            if (sub == 0)
                pre_rec[(t & 1) * 1024 + g * 256 + o] =
                    part + b_rec[g * HID + o] + s2r_lb[g * HID + o];
        }
        if (t + 1 < T_STEPS)
            oldpart[((t + 1) & 1) * 8192 + r * 256 + tid] = s_old;
    }
}

// ---------------- final: elementwise h_rec(255) + output projection ----------------
__global__ void k_final(const float* __restrict__ pre_rec,
                        const float* __restrict__ crec,
                        const float* __restrict__ W_out,
                        const float* __restrict__ b_out,
                        const float* __restrict__ y_true,
                        float* __restrict__ out) {
    __shared__ float red[256];
    int o = threadIdx.x;
    const float* pre = pre_rec + ((T_STEPS - 1) & 1) * 1024;   // pre_rec(255)
    float pi = pre[o], pf = pre[256 + o], pc = pre[512 + o], po = pre[768 + o];
    float cp = crec[(T_STEPS & 1) * 256 + o];                  // crec(254)
    float cn = sigm(pf) * cp + sigm(pi) * tanh_(pc);
    float h = sigm(po) * tanh_(cn);
    for (int j = 0; j < 2; j++) {
        red[o] = h * W_out[o * 2 + j];
        __syncthreads();
        for (int s = 128; s > 0; s >>= 1) {
            if (o < s) red[o] += red[o + s];
            __syncthreads();
        }
        if (o == 0) out[j] = red[0] + b_out[j];
        __syncthreads();
    }
    if (o < 2) out[2 + o] = y_true[o];
}

extern "C" void kernel_launch(void* const* d_in, const int* in_sizes, int n_in,
                              void* d_out, int out_size, void* d_ws, size_t ws_size,
                              hipStream_t stream) {
    (void)in_sizes; (void)n_in; (void)out_size; (void)ws_size;
    const float* x_rec  = (const float*)d_in[0];
    const float* x_sat  = (const float*)d_in[1];
    const float* y_true = (const float*)d_in[2];
    const float* W_rec  = (const float*)d_in[3];
    const float* b_rec  = (const float*)d_in[4];
    const float* W_sat  = (const float*)d_in[5];
    const float* b_sat  = (const float*)d_in[6];
    const float* s2r_lw = (const float*)d_in[7];
    const float* s2r_lb = (const float*)d_in[8];
    const float* s2r_rw = (const float*)d_in[9];
    const float* r2s_lw = (const float*)d_in[10];
    const float* r2s_lb = (const float*)d_in[11];
    const float* r2s_rw = (const float*)d_in[12];
    const float* W_out  = (const float*)d_in[13];
    const float* b_out  = (const float*)d_in[14];
    const int*   s_ids  = (const int*)d_in[15];

    float* ws = (float*)d_ws;
    size_t off = 0;
    // ---- zeroed prefix ----
    float*    meanN    = ws + off;              off += 4096;    // [2][8*256]
    float*    oldpart  = ws + off;              off += 16384;   // [2][32*256]
    float*    crec     = ws + off;              off += 512;     // [2][256]
    float*    pre_rec  = ws + off;              off += 2048;    // [2][1024]
    int*      old_cnt  = (int*)(ws + off);      off += 256;
    int*      lv_cnt   = (int*)(ws + off);      off += 256;
    ushort_t* Hg_bf    = (ushort_t*)(ws + off); off += 262144;  // 2048*256 u16
    ushort_t* Cg_bf    = (ushort_t*)(ws + off); off += 262144;  // 2048*256 u16
    ushort_t* pos_inv  = (ushort_t*)(ws + off); off += 262144;  // 256*2048 u16
    // ---- zero prefix ends here ----
    int*      asrc     = (int*)(ws + off);      off += 262144;  // [256][1024] int
    unsigned* nxt_bits = (unsigned*)(ws + off); off += 8192;    // [256][32] u32
    short*    old_src  = (short*)(ws + off);    off += 131072;  // [256][1024] s16
    int*      lv       = (int*)(ws + off);      off += 262144;  // [256][1024] int
    ushort_t* HnewA    = (ushort_t*)(ws + off); off += 131072;  // 1024*256 u16
    ushort_t* HnewB    = (ushort_t*)(ws + off); off += 131072;
    ushort_t* CnewA    = (ushort_t*)(ws + off); off += 131072;  // 1024*256 u16
    ushort_t* CnewB    = (ushort_t*)(ws + off); off += 131072;
    ushort_t* BsatT    = (ushort_t*)(ws + off); off += 147456;  // 1024*288 u16
    ushort_t* rlw_bf   = (ushort_t*)(ws + off); off += 131072;  // [1024][256] u16
    float*    biasC    = ws + off;              off += 1024;
    ushort_t* s2r_rwT  = (ushort_t*)(ws + off); off += 131072;  // bf16 [4][256][256]
    ushort_t* s2r_lwT  = (ushort_t*)(ws + off); off += 131072;
    float*    W_recT   = ws + off;              off += 32768;   // 4*256*32

    const size_t zcount = 4096 + 16384 + 512 + 2048 + 256 + 256
                        + 262144 + 262144 + 262144;
    hipLaunchKernelGGL(k_zero, dim3(2048), dim3(256), 0, stream, ws, zcount);
    hipLaunchKernelGGL(k_inv, dim3(T_STEPS), dim3(256), 0, stream, s_ids, pos_inv);
    hipLaunchKernelGGL(k_idx, dim3(T_STEPS), dim3(256), 0, stream, s_ids, pos_inv,
                       asrc, nxt_bits, old_src, old_cnt, lv, lv_cnt);
    hipLaunchKernelGGL(k_bconv, dim3(1024), dim3(256), 0, stream, r2s_rw, W_sat, BsatT);
    hipLaunchKernelGGL(k_rlw, dim3(1024), dim3(256), 0, stream, r2s_lw, rlw_bf);
    hipLaunchKernelGGL(k_biasC, dim3(4), dim3(256), 0, stream, r2s_lb, b_sat, biasC);
    hipLaunchKernelGGL(k_wtb, dim3(8, 8, 4), dim3(256), 0, stream, s2r_rw, s2r_rwT);
    hipLaunchKernelGGL(k_wtb, dim3(8, 8, 4), dim3(256), 0, stream, s2r_lw, s2r_lwT);
    hipLaunchKernelGGL(k_wrt, dim3(4), dim3(256), 0, stream, W_rec, W_recT);

    for (int t = 0; t < T_STEPS; t++) {
        const ushort_t* HnP = (t & 1) ? HnewA : HnewB;
        ushort_t*       HnC = (t & 1) ? HnewB : HnewA;
        const ushort_t* CnP = (t & 1) ? CnewA : CnewB;
        ushort_t*       CnC = (t & 1) ? CnewB : CnewA;
        hipLaunchKernelGGL(k_step, dim3(288), dim3(256), 0, stream,
                           t, x_rec, x_sat, b_rec, s2r_lb,
                           asrc, nxt_bits, old_src, old_cnt, lv, lv_cnt,
                           BsatT, rlw_bf, biasC,
                           s2r_rwT, s2r_lwT, W_recT,
                           meanN, oldpart, crec, pre_rec,
                           Hg_bf, Cg_bf, HnP, HnC, CnP, CnC);
    }
    hipLaunchKernelGGL(k_final, dim3(1), dim3(256), 0, stream,
                       pre_rec, crec, W_out, b_out, y_true, (float*)d_out);
}

// Round 13
// 3422.824 us; speedup vs baseline: 1.0563x; 1.0104x over previous
//
#include <hip/hip_runtime.h>
#include <cstddef>

#define T_STEPS  256
#define NSAT     1024
#define GSAT     2048
#define HID      256
#define IN_DIM   32
#define KTOT     288   // 256 h_sat + 32 x_sat

typedef short  s16x8 __attribute__((ext_vector_type(8)));
typedef short  s16x4 __attribute__((ext_vector_type(4)));
typedef float  f32x4 __attribute__((ext_vector_type(4)));
typedef unsigned short ushort_t;

__device__ inline ushort_t f2bf(float f) {
    unsigned u = __builtin_bit_cast(unsigned, f);
    u += 0x7fffu + ((u >> 16) & 1u);
    return (ushort_t)(u >> 16);
}
__device__ inline float bf2f(ushort_t h) {
    unsigned u = ((unsigned)h) << 16;
    return __builtin_bit_cast(float, u);
}
__device__ inline float sigm(float x) { return 1.f / (1.f + __expf(-x)); }
__device__ inline float tanh_(float x) {
    float a = fabsf(x);
    float e = __expf(-2.f * a);
    float r = (1.f - e) / (1.f + e);
    return copysignf(r, x);
}

// ---------------- init: zero prefix ----------------
__global__ void k_zero(float* p, size_t n) {
    size_t i = (size_t)blockIdx.x * blockDim.x + threadIdx.x;
    size_t stride = (size_t)gridDim.x * blockDim.x;
    for (; i < n; i += stride) p[i] = 0.f;
}

// col order: c = (o>>3)*32 + g*8 + (o&7)  <->  g=(c>>3)&3, o=(c>>5)*8+(c&7)
__global__ void k_bconv(const float* __restrict__ r2s_rw,
                        const float* __restrict__ W_sat,
                        ushort_t* __restrict__ BsatT) {
    int c = blockIdx.x;
    int g = (c >> 3) & 3, o = (c >> 5) * 8 + (c & 7);
    for (int k = threadIdx.x; k < KTOT; k += 256) {
        float v = (k < 256) ? r2s_rw[((size_t)g * 256 + k) * 256 + o]
                            : W_sat[((size_t)g * 32 + (k - 256)) * 256 + o];
        BsatT[(size_t)c * KTOT + k] = f2bf(v);
    }
}

// rlw_bf[c][h] = r2s_lw[g][h][o], bf16 (col-major for in-sat rl matvec)
__global__ void k_rlw(const float* __restrict__ r2s_lw, ushort_t* __restrict__ rlw_bf) {
    int c = blockIdx.x;
    int g = (c >> 3) & 3, o = (c >> 5) * 8 + (c & 7);
    int h = threadIdx.x;
    rlw_bf[(size_t)c * 256 + h] = f2bf(r2s_lw[((size_t)g * 256 + h) * 256 + o]);
}

__global__ void k_biasC(const float* __restrict__ r2s_lb, const float* __restrict__ b_sat,
                        float* __restrict__ biasC) {
    int c = blockIdx.x * 256 + threadIdx.x;
    if (c < 1024) {
        int g = (c >> 3) & 3, o = (c >> 5) * 8 + (c & 7);
        biasC[c] = r2s_lb[g * 256 + o] + b_sat[g * 256 + o];
    }
}

__global__ void k_inv(const int* __restrict__ s_ids, ushort_t* __restrict__ pos_inv) {
    int t = blockIdx.x;
    for (int n = threadIdx.x; n < NSAT; n += 256)
        pos_inv[(size_t)t * GSAT + s_ids[(size_t)t * NSAT + n]] = (ushort_t)(n + 1);
}

// merged index precompute: asrc, nxt_bits, old list, leave list (per t)
__global__ void k_idx(const int* __restrict__ s_ids, const ushort_t* __restrict__ pos_inv,
                      int* __restrict__ asrc, unsigned* __restrict__ nxt_bits,
                      short* __restrict__ old_src, int* __restrict__ old_cnt,
                      int* __restrict__ lv, int* __restrict__ lv_cnt) {
    int t = blockIdx.x, tid = threadIdx.x;
    for (int n = tid; n < NSAT; n += 256) {
        int j = s_ids[(size_t)t * NSAT + n];
        int e = 1024 + j;
        if (t > 0) {
            int p = (int)pos_inv[(size_t)(t - 1) * GSAT + j] - 1;
            if (p >= 0) e = p;
        }
        asrc[(size_t)t * NSAT + n] = e;
    }
    if (tid < 32) {
        unsigned bits = 0;
        if (t + 1 < T_STEPS) {
            for (int i = 0; i < 32; i++) {
                int j = s_ids[(size_t)t * NSAT + tid * 32 + i];
                if (pos_inv[(size_t)(t + 1) * GSAT + j] > 0) bits |= (1u << i);
            }
        }
        nxt_bits[t * 32 + tid] = bits;
    }
    if (t + 1 < T_STEPS) {
        for (int n = tid; n < NSAT; n += 256) {
            int j = s_ids[(size_t)(t + 1) * NSAT + n];
            if (pos_inv[(size_t)t * GSAT + j] == 0) {
                int slot = atomicAdd(&old_cnt[t], 1);
                short e = (short)(-(j + 1));
                if (t > 0) {
                    int p = (int)pos_inv[(size_t)(t - 1) * GSAT + j] - 1;
                    if (p >= 0) e = (short)p;
                }
                old_src[(size_t)t * NSAT + slot] = e;
            }
        }
    }
    if (t > 0) {
        for (int n = tid; n < NSAT; n += 256) {
            int j = s_ids[(size_t)(t - 1) * NSAT + n];
            if (pos_inv[(size_t)t * GSAT + j] == 0) {
                int slot = atomicAdd(&lv_cnt[t], 1);
                lv[(size_t)t * NSAT + slot] = (n << 16) | j;
            }
        }
    }
}

// transpose [4][256][256] (g,h,o) -> (g,o,h), bf16 output
__global__ void k_wtb(const float* __restrict__ in, ushort_t* __restrict__ outT) {
    __shared__ float tl[32][33];
    int g = blockIdx.z;
    int h0 = blockIdx.x * 32, o0 = blockIdx.y * 32;
    int lx = threadIdx.x & 31, ly = threadIdx.x >> 5;
#pragma unroll
    for (int i = 0; i < 32; i += 8)
        tl[ly + i][lx] = in[((size_t)g * 256 + h0 + ly + i) * 256 + o0 + lx];
    __syncthreads();
#pragma unroll
    for (int i = 0; i < 32; i += 8)
        outT[((size_t)g * 256 + o0 + ly + i) * 256 + h0 + lx] = f2bf(tl[lx][ly + i]);
}

__global__ void k_wrt(const float* __restrict__ W_rec, float* __restrict__ W_recT) {
    int idx = blockIdx.x * 256 + threadIdx.x;
    int g = idx >> 8, o = idx & 255;
#pragma unroll
    for (int i = 0; i < 32; i++)
        W_recT[(size_t)idx * 32 + i] = W_rec[((size_t)g * 32 + i) * 256 + o];
}

// ---------------- per-step kernel: grid 288 (256 sat + 32 rec), no cross-block waits
// R10 phase order (A-gathers issue at entry, NO barrier before the GEMM) +
// parallel meanN reduce + vectorized rl LDS reads.
__launch_bounds__(256)
__global__ void k_step(int t,
    const float* __restrict__ x_rec, const float* __restrict__ x_sat,
    const float* __restrict__ b_rec, const float* __restrict__ s2r_lb,
    const int* __restrict__ asrc, const unsigned* __restrict__ nxt_bits,
    const short* __restrict__ old_src, const int* __restrict__ old_cnt,
    const int* __restrict__ lv, const int* __restrict__ lv_cnt,
    const ushort_t* __restrict__ BsatT, const ushort_t* __restrict__ rlw_bf,
    const float* __restrict__ biasC,
    const ushort_t* __restrict__ s2r_rwT, const ushort_t* __restrict__ s2r_lwT,
    const float* __restrict__ W_recT,
    float* __restrict__ meanN,    // [2][8*256]
    float* __restrict__ oldpart,  // [2][32*256]
    float* __restrict__ crec,     // [2][256]
    float* __restrict__ pre_rec,  // [2][1024]
    ushort_t* __restrict__ Hg_bf, ushort_t* __restrict__ Cg_bf,
    const ushort_t* __restrict__ HnP, ushort_t* __restrict__ HnC,
    const ushort_t* __restrict__ CnP, ushort_t* __restrict__ CnC)
{
    const int b = blockIdx.x, tid = threadIdx.x;
    const float* preP  = pre_rec + ((t + 1) & 1) * 1024;  // pre_rec(t-1)
    const float* crecP = crec + (t & 1) * 256;            // crec(t-2)

    if (b < 256) {
        // ================= satellite block: by row-group, bxc col-group =========
        const int by = b >> 5, bxc = b & 31;
        __shared__ alignas(16) ushort_t hr_bfs[256];
        __shared__ float    bias_s[32];
        __shared__ float    rl_s[32];
        __shared__ float    pre_s[128][33];

        const int w = tid >> 6, l = tid & 63;
        const int lr = l & 15, kb = (l >> 4) * 8;
        const int r0 = w * 32 + lr, r1 = r0 + 16;
        const int* asrc_t = asrc + (size_t)t * NSAT + by * 128;

        // ---- entry: issue ALL independent loads (A-gather chain first) ----
        const int e0 = asrc_t[r0], e1 = asrc_t[r1];
        if (tid < 32) bias_s[tid] = biasC[bxc * 32 + tid];
        const int n_ep = tid >> 1, oi0_ep = (tid & 1) * 4;
        const int og0_ep = bxc * 8 + oi0_ep;
        const int en_ep = asrc_t[n_ep];
        const ushort_t* csrc = (en_ep < 1024) ? CnP + (size_t)en_ep * HID + og0_ep
                                              : Cg_bf + (size_t)(en_ep - 1024) * HID + og0_ep;
        s16x4 cold4 = *(const s16x4*)csrc;
        const int gr_ep = by * 128 + n_ep;
        const bool nxt = (t + 1 < T_STEPS) &&
                         ((nxt_bits[t * 32 + (gr_ep >> 5)] >> (gr_ep & 31)) & 1u);
        // lazy-park preload (rows leaving the visible set)
        const int lv_m = lv_cnt[t];
        ushort_t pH[4], pC[4]; int pJ[4];
#pragma unroll
        for (int i = 0; i < 4; i++) {
            int k = b + i * 256;
            if (k < lv_m) {
                int pv = lv[(size_t)t * NSAT + k];
                int pos = pv >> 16; pJ[i] = pv & 0xffff;
                pH[i] = HnP[(size_t)pos * HID + tid];
                pC[i] = CnP[(size_t)pos * HID + tid];
            } else pJ[i] = -1;
        }
        // h_rec(t-1) recompute (overlaps the A/B gathers; no barrier here)
        {
            float h = 0.f;
            if (t > 0) {
                float pi = preP[tid], pf = preP[256 + tid], pc = preP[512 + tid], po = preP[768 + tid];
                float cp = (t >= 2) ? crecP[tid] : 0.f;
                float cn = sigm(pf) * cp + sigm(pi) * tanh_(pc);
                h = sigm(po) * tanh_(cn);
            }
            hr_bfs[tid] = f2bf(h);
        }

        // --- MFMA GEMM: 128 rows x 32 gate-cols, K = 256(h) + 32(x) ---
        const ushort_t* a0 = (e0 < 1024) ? HnP + (size_t)e0 * HID : Hg_bf + (size_t)(e0 - 1024) * HID;
        const ushort_t* a1 = (e1 < 1024) ? HnP + (size_t)e1 * HID : Hg_bf + (size_t)(e1 - 1024) * HID;
        const ushort_t* bp0 = BsatT + ((size_t)(bxc * 32 + lr)) * KTOT;
        const ushort_t* bp1 = bp0 + (size_t)16 * KTOT;
        f32x4 a00 = {0.f,0.f,0.f,0.f}, a01 = a00, a10 = a00, a11 = a00;
#pragma unroll
        for (int kc = 0; kc < 8; kc++) {
            int k0 = kc * 32 + kb;
            s16x8 af0 = *(const s16x8*)(a0 + k0);
            s16x8 af1 = *(const s16x8*)(a1 + k0);
            s16x8 bv0 = *(const s16x8*)(bp0 + k0);
            s16x8 bv1 = *(const s16x8*)(bp1 + k0);
            a00 = __builtin_amdgcn_mfma_f32_16x16x32_bf16(af0, bv0, a00, 0, 0, 0);
            a01 = __builtin_amdgcn_mfma_f32_16x16x32_bf16(af0, bv1, a01, 0, 0, 0);
            a10 = __builtin_amdgcn_mfma_f32_16x16x32_bf16(af1, bv0, a10, 0, 0, 0);
            a11 = __builtin_amdgcn_mfma_f32_16x16x32_bf16(af1, bv1, a11, 0, 0, 0);
        }
        {   // x segment (K = 256..287)
            const float* ax0 = x_sat + ((size_t)t * NSAT + by * 128 + r0) * IN_DIM + kb;
            const float* ax1 = x_sat + ((size_t)t * NSAT + by * 128 + r1) * IN_DIM + kb;
            f32x4 x00 = *(const f32x4*)ax0, x01 = *(const f32x4*)(ax0 + 4);
            f32x4 x10 = *(const f32x4*)ax1, x11 = *(const f32x4*)(ax1 + 4);
            s16x8 af0, af1;
#pragma unroll
            for (int e = 0; e < 4; e++) {
                af0[e] = (short)f2bf(x00[e]); af0[4 + e] = (short)f2bf(x01[e]);
                af1[e] = (short)f2bf(x10[e]); af1[4 + e] = (short)f2bf(x11[e]);
            }
            int k0 = 256 + kb;
            s16x8 bv0 = *(const s16x8*)(bp0 + k0);
            s16x8 bv1 = *(const s16x8*)(bp1 + k0);
            a00 = __builtin_amdgcn_mfma_f32_16x16x32_bf16(af0, bv0, a00, 0, 0, 0);
            a01 = __builtin_amdgcn_mfma_f32_16x16x32_bf16(af0, bv1, a01, 0, 0, 0);
            a10 = __builtin_amdgcn_mfma_f32_16x16x32_bf16(af1, bv0, a10, 0, 0, 0);
            a11 = __builtin_amdgcn_mfma_f32_16x16x32_bf16(af1, bv1, a11, 0, 0, 0);
        }
        // stage C (col=lane&15, row=(lane>>4)*4+reg)
#pragma unroll
        for (int rr = 0; rr < 4; rr++) {
            int ro = (l >> 4) * 4 + rr;
            pre_s[w * 32 + ro][lr]           = a00[rr];
            pre_s[w * 32 + ro][16 + lr]      = a01[rr];
            pre_s[w * 32 + 16 + ro][lr]      = a10[rr];
            pre_s[w * 32 + 16 + ro][16 + lr] = a11[rr];
        }
        __syncthreads();   // publish pre_s + hr_bfs + bias_s

        // --- rl matvec: rl[c] = r2s_lw^T.h_rec(t-1) + (r2s_lb + b_sat) ---
        {
            int c = tid >> 3, sub = tid & 7;
            const ushort_t* wp = rlw_bf + ((size_t)(bxc * 32 + c)) * 256 + sub * 32;
            const ushort_t* hp = hr_bfs + sub * 32;
            float acc = 0.f;
#pragma unroll
            for (int q = 0; q < 4; q++) {
                s16x8 wv = *(const s16x8*)(wp + q * 8);
                s16x8 hv = *(const s16x8*)(hp + q * 8);
#pragma unroll
                for (int e = 0; e < 8; e++)
                    acc += bf2f((ushort_t)hv[e]) * bf2f((ushort_t)wv[e]);
            }
            acc += __shfl_down(acc, 4);
            acc += __shfl_down(acc, 2);
            acc += __shfl_down(acc, 1);
            if (sub == 0) rl_s[c] = acc + bias_s[c];
        }
        __syncthreads();   // publish rl_s

        // --- epilogue: LSTM over 4 cells/thread (cold-C preloaded, bf16) ---
        {
            int n = n_ep, oi0 = oi0_ep, og0 = og0_ep;
            f32x4 hf; s16x4 cnew, hnew;
#pragma unroll
            for (int e = 0; e < 4; e++) {
                int oi = oi0 + e;
                float pi = pre_s[n][oi]      + rl_s[oi];
                float pf = pre_s[n][8 + oi]  + rl_s[8 + oi];
                float pc = pre_s[n][16 + oi] + rl_s[16 + oi];
                float po = pre_s[n][24 + oi] + rl_s[24 + oi];
                float ig = sigm(pi), fg = sigm(pf), tg = tanh_(pc), oo = sigm(po);
                float cn = fg * bf2f((ushort_t)cold4[e]) + ig * tg;
                float hn = oo * tanh_(cn);
                hf[e] = hn;
                cnew[e] = (short)f2bf(cn);
                hnew[e] = (short)f2bf(hn);
            }
            *(s16x4*)(CnC + (size_t)gr_ep * HID + og0) = cnew;
            *(s16x4*)(HnC + (size_t)gr_ep * HID + og0) = hnew;
#pragma unroll
            for (int e = 0; e < 4; e++) pre_s[n_ep][oi0_ep + e] = nxt ? hf[e] : 0.f;
        }
        __syncthreads();
        // --- meanN: parallel reduce, 8 col-groups x 32 lanes ---
        if (t + 1 < T_STEPS) {
            int c = tid >> 5, lane = tid & 31;
            float s = pre_s[lane][c] + pre_s[lane + 32][c]
                    + pre_s[lane + 64][c] + pre_s[lane + 96][c];
            s += __shfl_down(s, 16, 32);
            s += __shfl_down(s, 8, 32);
            s += __shfl_down(s, 4, 32);
            s += __shfl_down(s, 2, 32);
            s += __shfl_down(s, 1, 32);
            if (lane == 0)
                meanN[((t + 1) & 1) * 2048 + by * 256 + bxc * 8 + c] = s;
        }

        // --- lazy park of departing rows (values preloaded at entry) ---
#pragma unroll
        for (int i = 0; i < 4; i++) {
            if (pJ[i] >= 0) {
                Hg_bf[(size_t)pJ[i] * HID + tid] = pH[i];
                Cg_bf[(size_t)pJ[i] * HID + tid] = pC[i];
            }
        }
    } else {
        // ================= rec block r: mean reduce -> oldpart(t+1) -> pre_rec(t) ==
        const int r = b - 256;
        __shared__ float mean_s[256], hr_s[256], xr_s[32];
        const int m_old = (t + 1 < T_STEPS) ? old_cnt[t] : 0;   // issued first
        {   // reduce mean(t) from prev-launch partials
            float s = 0.f;
            const float* mp = meanN + (t & 1) * 2048;
#pragma unroll
            for (int p = 0; p < 8; p++) s += mp[p * 256 + tid];
            const float* op = oldpart + (t & 1) * 8192;
#pragma unroll 8
            for (int p = 0; p < 32; p++) s += op[p * 256 + tid];
            mean_s[tid] = s * (1.f / 1024.f);
        }
        {   // elementwise h_rec(t-1); block r==0 stores crec(t-1)
            float h = 0.f, cn = 0.f;
            if (t > 0) {
                float pi = preP[tid], pf = preP[256 + tid], pc = preP[512 + tid], po = preP[768 + tid];
                float cp = (t >= 2) ? crecP[tid] : 0.f;
                cn = sigm(pf) * cp + sigm(pi) * tanh_(pc);
                h = sigm(po) * tanh_(cn);
            }
            hr_s[tid] = h;
            if (r == 0 && t > 0) crec[((t + 1) & 1) * 256 + tid] = cn;
        }
        if (tid < 32) xr_s[tid] = x_rec[(size_t)t * IN_DIM + tid];
        __syncthreads();
        // oldpart(t+1) gather issued BEFORE the matvec: latency hides under it
        float s_old = 0.f;
        {
            const short* osp = old_src + (size_t)t * NSAT;
#pragma unroll 2
            for (int k = r; k < m_old; k += 32) {
                int e = osp[k];
                const ushort_t* hp = (e >= 0) ? HnP + (size_t)e * HID
                                              : Hg_bf + (size_t)(-(e + 1)) * HID;
                s_old += bf2f(hp[tid]);
            }
        }
        {   // pre_rec(t) matvec: 32 gate-outs per block (bf16 weights)
            const int combo = tid >> 3, sub = tid & 7;
            const int g = combo >> 3, oo = combo & 7;
            const int o = r * 8 + oo;
            const ushort_t* rwp = s2r_rwT + ((size_t)(g * 256 + o)) * 256 + sub * 32;
            const ushort_t* lwp = s2r_lwT + ((size_t)(g * 256 + o)) * 256 + sub * 32;
            float part = 0.f;
#pragma unroll
            for (int q = 0; q < 4; q++) {
                s16x8 a = *(const s16x8*)(rwp + q * 8);
                s16x8 c = *(const s16x8*)(lwp + q * 8);
#pragma unroll
                for (int e = 0; e < 8; e++) {
                    int h = sub * 32 + q * 8 + e;
                    part += hr_s[h] * bf2f((ushort_t)a[e]) + mean_s[h] * bf2f((ushort_t)c[e]);
                }
            }
            {
                f32x4 wx = *(const f32x4*)(W_recT + ((size_t)(g * 256 + o)) * 32 + sub * 4);
#pragma unroll
                for (int e = 0; e < 4; e++) part += xr_s[sub * 4 + e] * wx[e];
            }
            part += __shfl_down(part, 4);
            part += __shfl_down(part, 2);
            part += __shfl_down(part, 1);
            if (sub == 0)
                pre_rec[(t & 1) * 1024 + g * 256 + o] =
                    part + b_rec[g * HID + o] + s2r_lb[g * HID + o];
        }
        if (t + 1 < T_STEPS)
            oldpart[((t + 1) & 1) * 8192 + r * 256 + tid] = s_old;
    }
}

// ---------------- final: elementwise h_rec(255) + output projection ----------------
__global__ void k_final(const float* __restrict__ pre_rec,
                        const float* __restrict__ crec,
                        const float* __restrict__ W_out,
                        const float* __restrict__ b_out,
                        const float* __restrict__ y_true,
                        float* __restrict__ out) {
    __shared__ float red[256];
    int o = threadIdx.x;
    const float* pre = pre_rec + ((T_STEPS - 1) & 1) * 1024;   // pre_rec(255)
    float pi = pre[o], pf = pre[256 + o], pc = pre[512 + o], po = pre[768 + o];
    float cp = crec[(T_STEPS & 1) * 256 + o];                  // crec(254)
    float cn = sigm(pf) * cp + sigm(pi) * tanh_(pc);
    float h = sigm(po) * tanh_(cn);
    for (int j = 0; j < 2; j++) {
        red[o] = h * W_out[o * 2 + j];
        __syncthreads();
        for (int s = 128; s > 0; s >>= 1) {
            if (o < s) red[o] += red[o + s];
            __syncthreads();
        }
        if (o == 0) out[j] = red[0] + b_out[j];
        __syncthreads();
    }
    if (o < 2) out[2 + o] = y_true[o];
}

extern "C" void kernel_launch(void* const* d_in, const int* in_sizes, int n_in,
                              void* d_out, int out_size, void* d_ws, size_t ws_size,
                              hipStream_t stream) {
    (void)in_sizes; (void)n_in; (void)out_size; (void)ws_size;
    const float* x_rec  = (const float*)d_in[0];
    const float* x_sat  = (const float*)d_in[1];
    const float* y_true = (const float*)d_in[2];
    const float* W_rec  = (const float*)d_in[3];
    const float* b_rec  = (const float*)d_in[4];
    const float* W_sat  = (const float*)d_in[5];
    const float* b_sat  = (const float*)d_in[6];
    const float* s2r_lw = (const float*)d_in[7];
    const float* s2r_lb = (const float*)d_in[8];
    const float* s2r_rw = (const float*)d_in[9];
    const float* r2s_lw = (const float*)d_in[10];
    const float* r2s_lb = (const float*)d_in[11];
    const float* r2s_rw = (const float*)d_in[12];
    const float* W_out  = (const float*)d_in[13];
    const float* b_out  = (const float*)d_in[14];
    const int*   s_ids  = (const int*)d_in[15];

    float* ws = (float*)d_ws;
    size_t off = 0;
    // ---- zeroed prefix ----
    float*    meanN    = ws + off;              off += 4096;    // [2][8*256]
    float*    oldpart  = ws + off;              off += 16384;   // [2][32*256]
    float*    crec     = ws + off;              off += 512;     // [2][256]
    float*    pre_rec  = ws + off;              off += 2048;    // [2][1024]
    int*      old_cnt  = (int*)(ws + off);      off += 256;
    int*      lv_cnt   = (int*)(ws + off);      off += 256;
    ushort_t* Hg_bf    = (ushort_t*)(ws + off); off += 262144;  // 2048*256 u16
    ushort_t* Cg_bf    = (ushort_t*)(ws + off); off += 262144;  // 2048*256 u16
    ushort_t* pos_inv  = (ushort_t*)(ws + off); off += 262144;  // 256*2048 u16
    // ---- zero prefix ends here ----
    int*      asrc     = (int*)(ws + off);      off += 262144;  // [256][1024] int
    unsigned* nxt_bits = (unsigned*)(ws + off); off += 8192;    // [256][32] u32
    short*    old_src  = (short*)(ws + off);    off += 131072;  // [256][1024] s16
    int*      lv       = (int*)(ws + off);      off += 262144;  // [256][1024] int
    ushort_t* HnewA    = (ushort_t*)(ws + off); off += 131072;  // 1024*256 u16
    ushort_t* HnewB    = (ushort_t*)(ws + off); off += 131072;
    ushort_t* CnewA    = (ushort_t*)(ws + off); off += 131072;  // 1024*256 u16
    ushort_t* CnewB    = (ushort_t*)(ws + off); off += 131072;
    ushort_t* BsatT    = (ushort_t*)(ws + off); off += 147456;  // 1024*288 u16
    ushort_t* rlw_bf   = (ushort_t*)(ws + off); off += 131072;  // [1024][256] u16
    float*    biasC    = ws + off;              off += 1024;
    ushort_t* s2r_rwT  = (ushort_t*)(ws + off); off += 131072;  // bf16 [4][256][256]
    ushort_t* s2r_lwT  = (ushort_t*)(ws + off); off += 131072;
    float*    W_recT   = ws + off;              off += 32768;   // 4*256*32

    const size_t zcount = 4096 + 16384 + 512 + 2048 + 256 + 256
                        + 262144 + 262144 + 262144;
    hipLaunchKernelGGL(k_zero, dim3(2048), dim3(256), 0, stream, ws, zcount);
    hipLaunchKernelGGL(k_inv, dim3(T_STEPS), dim3(256), 0, stream, s_ids, pos_inv);
    hipLaunchKernelGGL(k_idx, dim3(T_STEPS), dim3(256), 0, stream, s_ids, pos_inv,
                       asrc, nxt_bits, old_src, old_cnt, lv, lv_cnt);
    hipLaunchKernelGGL(k_bconv, dim3(1024), dim3(256), 0, stream, r2s_rw, W_sat, BsatT);
    hipLaunchKernelGGL(k_rlw, dim3(1024), dim3(256), 0, stream, r2s_lw, rlw_bf);
    hipLaunchKernelGGL(k_biasC, dim3(4), dim3(256), 0, stream, r2s_lb, b_sat, biasC);
    hipLaunchKernelGGL(k_wtb, dim3(8, 8, 4), dim3(256), 0, stream, s2r_rw, s2r_rwT);
    hipLaunchKernelGGL(k_wtb, dim3(8, 8, 4), dim3(256), 0, stream, s2r_lw, s2r_lwT);
    hipLaunchKernelGGL(k_wrt, dim3(4), dim3(256), 0, stream, W_rec, W_recT);

    for (int t = 0; t < T_STEPS; t++) {
        const ushort_t* HnP = (t & 1) ? HnewA : HnewB;
        ushort_t*       HnC = (t & 1) ? HnewB : HnewA;
        const ushort_t* CnP = (t & 1) ? CnewA : CnewB;
        ushort_t*       CnC = (t & 1) ? CnewB : CnewA;
        hipLaunchKernelGGL(k_step, dim3(288), dim3(256), 0, stream,
                           t, x_rec, x_sat, b_rec, s2r_lb,
                           asrc, nxt_bits, old_src, old_cnt, lv, lv_cnt,
                           BsatT, rlw_bf, biasC,
                           s2r_rwT, s2r_lwT, W_recT,
                           meanN, oldpart, crec, pre_rec,
                           Hg_bf, Cg_bf, HnP, HnC, CnP, CnC);
    }
    hipLaunchKernelGGL(k_final, dim3(1), dim3(256), 0, stream,
                       pre_rec, crec, W_out, b_out, y_true, (float*)d_out);
}